// Round 8
// baseline (175.853 us; speedup 1.0000x reference)
//
#include <hip/hip_runtime.h>
#include <hip/hip_bf16.h>

// Problem constants: B=8, N=128, D=512, L=48, 2 GCN layers.
//   t = einsum('ldk,bjk->bljd', w, h)  ==  T[(b*128+j), l*512+d] = sum_k H[bj,k]*Wflat[ld,k]
//   msg[b,i,d] = sum_j adj[b,i,j] * T[b*128+j, lab[b,i,j]*512+d];  h = relu(msg/(1+deg))
//   out = relu(relu(h@w0^T+b0)@w1^T+b1)
// Big GEMM: 2-phase 128x128 MFMA kernel + XCD L2-band map + depth-2 prefetch
//           (triple-buffered LDS, counted vmcnt(4), raw s_barrier).
// MLP: bf16 hi/lo compensation, split-K (deterministic fixed-order combine).

typedef unsigned short u16;
typedef unsigned int u32;
using bf16x8 = __bf16 __attribute__((ext_vector_type(8)));
using f32x4 = float __attribute__((ext_vector_type(4)));

__device__ __forceinline__ u16 f2bf(float f) {
  u32 u = __float_as_uint(f);
  u32 r = u + 0x7fffu + ((u >> 16) & 1u);   // round-to-nearest-even
  return (u16)(r >> 16);
}
__device__ __forceinline__ float bf2f(u16 h) {
  return __uint_as_float(((u32)h) << 16);
}

__device__ __forceinline__ void gl_lds16(const u16* g, u16* l) {
  __builtin_amdgcn_global_load_lds(
      (const __attribute__((address_space(1))) u32*)g,
      (__attribute__((address_space(3))) u32*)l, 16, 0, 0);
}

// ---------------- fp32 -> bf16 conversion (float4 vectorized) ----------------
__global__ __launch_bounds__(256)
void cvt_f32_bf16(const float* __restrict__ in, u16* __restrict__ out, int n4) {
  int stride = gridDim.x * blockDim.x;
  for (int i = blockIdx.x * blockDim.x + threadIdx.x; i < n4; i += stride) {
    float4 v = ((const float4*)in)[i];
    uint2 o;
    o.x = (u32)f2bf(v.x) | ((u32)f2bf(v.y) << 16);
    o.y = (u32)f2bf(v.z) | ((u32)f2bf(v.w) << 16);
    ((uint2*)out)[i] = o;
  }
}

// ---------------- MLP weight prep: hi/lo split into concatenated-K layout ----
// w0 (512x512 f32) -> Bp1 (512x1024 bf16): [n,k]=hi, [n,512+k]=lo
// w1 (512x512 f32) -> Bp2 (512x1536 bf16): [n,k]=hi, [n,512+k]=lo, [n,1024+k]=hi
__global__ __launch_bounds__(256)
void prep_mlp_w(const float* __restrict__ w0, const float* __restrict__ w1,
                u16* __restrict__ Bp1, u16* __restrict__ Bp2) {
  int idx = blockIdx.x * 256 + threadIdx.x;   // grid covers 2*262144
  if (idx < 262144) {
    const int n = idx >> 9, k = idx & 511;
    const float v = w0[idx];
    const u16 hi = f2bf(v);
    const float lo = v - bf2f(hi);
    Bp1[n * 1024 + k] = hi;
    Bp1[n * 1024 + 512 + k] = f2bf(lo);
  } else {
    const int j = idx - 262144;
    const int n = j >> 9, k = j & 511;
    const float v = w1[j];
    const u16 hi = f2bf(v);
    const float lo = v - bf2f(hi);
    Bp2[n * 1536 + k] = hi;
    Bp2[n * 1536 + 512 + k] = f2bf(lo);
    Bp2[n * 1536 + 1024 + k] = hi;
  }
}

// ---------------- bf16 NT GEMM: C[m,n] = sum_k A[m,k]*B[n,k] ----------------
// A: MxK row-major bf16, B: NxK row-major bf16.
// 128x128 tile, BK=32, 256 threads (4 waves, 2x2), 16x16x32 MFMA, 4x4 frags/wave.
// Depth-2 prefetch: 3 LDS buffers (48 KB), stage kt+2 each iter, end-of-iter
// wait vmcnt(4) (kt+1's 4 loads done, kt+2's in flight) + RAW s_barrier
// (no __syncthreads -> no compiler vmcnt(0) drain).
// MODE 0: big einsum. 1-D grid 1536; XCD band map (XCD x owns n-tiles
//         [24x,24x+24) x 8 m-tiles -> B band 3.1MB fits per-XCD L2). bf16 C.
// MODE 1: split-K partial. 3-D grid (N/128, M/128, S); K-chunk = KC;
//         fp32 partial store at C + z*1024*N (combined later, fixed order).
#define BM 128
#define BN 128
#define BK 32

template <int MODE>
__global__ __launch_bounds__(256)
void gemm_nt_bf16(const u16* __restrict__ A, const u16* __restrict__ B,
                  void* __restrict__ C, int N, int K, int KC) {
  __shared__ u16 sA[3][BM * BK];   // 8 KB per buffer
  __shared__ u16 sB[3][BN * BK];
  const int tid = threadIdx.x;
  const int lane = tid & 63;
  const int wid = tid >> 6;
  const int wm = wid >> 1;
  const int wn = wid & 1;

  int m0, n0, kc;
  if (MODE == 0) {
    // dispatch round-robins consecutive blockIdx across XCDs: XCD = bid % 8.
    // bid = r*8 + xcd -> XCD xcd gets r = 0..191: mt = r&7, n-band slot r>>3.
    const int bid = blockIdx.x;
    const int xcd = bid & 7;
    const int r = bid >> 3;
    m0 = (r & 7) * BM;                  // 8 m-tiles (M=1024)
    n0 = (xcd * 24 + (r >> 3)) * BN;    // 24 n-tiles per XCD band (N=24576)
    kc = 0;
  } else {
    m0 = blockIdx.y * BM;
    n0 = blockIdx.x * BN;
    kc = blockIdx.z;
  }

  const int srow = tid >> 2;
  const int scol = (tid & 3) * 8;
  const u16* gA0 = A + (size_t)(m0 + srow) * K + kc * KC + scol;
  const u16* gA1 = A + (size_t)(m0 + 64 + srow) * K + kc * KC + scol;
  const u16* gB0 = B + (size_t)(n0 + srow) * K + kc * KC + scol;
  const u16* gB1 = B + (size_t)(n0 + 64 + srow) * K + kc * KC + scol;

  auto stage = [&](int buf, int kt) {
    const int ko = kt * BK;
    gl_lds16(gA0 + ko, &sA[buf][tid * 8]);
    gl_lds16(gA1 + ko, &sA[buf][2048 + tid * 8]);
    gl_lds16(gB0 + ko, &sB[buf][tid * 8]);
    gl_lds16(gB1 + ko, &sB[buf][2048 + tid * 8]);
  };

  f32x4 acc[4][4];
#pragma unroll
  for (int i = 0; i < 4; ++i)
#pragma unroll
    for (int j = 0; j < 4; ++j)
      acc[i][j] = (f32x4){0.f, 0.f, 0.f, 0.f};

  const int NT = KC / BK;   // 16 (MODE 0), 8 (MODE 1)

  // prologue: stage kt0, kt1; wait kt0 (4 of kt1 stay in flight)
  stage(0, 0);
  if (NT > 1) {
    stage(1, 1);
    asm volatile("s_waitcnt vmcnt(4)" ::: "memory");
  } else {
    asm volatile("s_waitcnt vmcnt(0)" ::: "memory");
  }
  __builtin_amdgcn_s_barrier();
  __builtin_amdgcn_sched_barrier(0);

  const int r15 = lane & 15;
  const int ksub = (lane >> 4) * 8;
  for (int kt = 0; kt < NT; ++kt) {
    const int buf = kt % 3;
    if (kt + 2 < NT) stage((kt + 2) % 3, kt + 2);   // depth-2 prefetch

    bf16x8 af[4], bfr[4];
#pragma unroll
    for (int mi = 0; mi < 4; ++mi)
      af[mi] = *(const bf16x8*)&sA[buf][(wm * 64 + mi * 16 + r15) * BK + ksub];
#pragma unroll
    for (int ni = 0; ni < 4; ++ni)
      bfr[ni] = *(const bf16x8*)&sB[buf][(wn * 64 + ni * 16 + r15) * BK + ksub];

#pragma unroll
    for (int mi = 0; mi < 4; ++mi)
#pragma unroll
      for (int ni = 0; ni < 4; ++ni)
        acc[mi][ni] = __builtin_amdgcn_mfma_f32_16x16x32_bf16(
            af[mi], bfr[ni], acc[mi][ni], 0, 0, 0);

    if (kt + 1 < NT) {
      // need kt+1's 4 loads done; kt+2's (if issued) may stay in flight
      if (kt + 2 < NT)
        asm volatile("s_waitcnt vmcnt(4)" ::: "memory");
      else
        asm volatile("s_waitcnt vmcnt(0)" ::: "memory");
      __builtin_amdgcn_s_barrier();
      __builtin_amdgcn_sched_barrier(0);
    }
  }

  // epilogue: C/D layout col=lane&15, row=(lane>>4)*4+reg  [m89-verified]
  const int rq = (lane >> 4) * 4;
#pragma unroll
  for (int mi = 0; mi < 4; ++mi) {
#pragma unroll
    for (int ni = 0; ni < 4; ++ni) {
      const int row = m0 + wm * 64 + mi * 16 + rq;
      const int col = n0 + wn * 64 + ni * 16 + r15;
      f32x4 v = acc[mi][ni];
      if (MODE == 0) {
        u16* Cb = (u16*)C;
        const size_t base = (size_t)row * N + col;
#pragma unroll
        for (int r = 0; r < 4; ++r)
          Cb[base + (size_t)r * N] = f2bf(v[r]);
      } else {
        float* Cf = (float*)C + (size_t)kc * 1024 * N;
#pragma unroll
        for (int r = 0; r < 4; ++r)
          Cf[(size_t)(row + r) * N + col] = v[r];
      }
    }
  }
}

// ---------------- per-row gather-reduce: msg + relu(msg/denom) -> bf16 -------
// block -> (b,i) with b = bid&7 so each XCD's L2 holds mostly one b's T slice.
// Skips adj==0 edges (bit-exact: skipped terms added exactly 0.0).
template <bool DUP>
__global__ __launch_bounds__(256)
void gcn_agg(const u16* __restrict__ T, const float* __restrict__ adj,
             const int* __restrict__ lab, u16* __restrict__ Hout) {
  const int bid = blockIdx.x;
  const int b = bid & 7;
  const int i = bid >> 3;
  const int bi = b * 128 + i;
  const int tid = threadIdx.x;
  __shared__ float s_adj[128];
  __shared__ int s_off[128];
  if (tid < 128) {
    s_adj[tid] = adj[(size_t)bi * 128 + tid];
    const int lv = lab[(size_t)bi * 128 + tid];
    s_off[tid] = ((b * 128 + tid) * 48 + lv) * 512;
  }
  __syncthreads();

  const int d = tid * 2;
  float den = 1.0f, a0 = 0.f, a1 = 0.f;
#pragma unroll 4
  for (int j = 0; j < 128; ++j) {
    const float a = s_adj[j];
    if (a != 0.0f) {              // block-uniform branch; a is exactly 1.0
      den += 1.0f;
      const u32 u = *(const u32*)&T[(size_t)s_off[j] + d];
      a0 += __uint_as_float((u & 0xffffu) << 16);
      a1 += __uint_as_float(u & 0xffff0000u);
    }
  }
  const float r = 1.0f / den;
  a0 = fmaxf(a0 * r, 0.0f);
  a1 = fmaxf(a1 * r, 0.0f);
  const u32 o = (u32)f2bf(a0) | ((u32)f2bf(a1) << 16);
  if (DUP) {
    *(u32*)&Hout[(size_t)bi * 1024 + d] = o;
    *(u32*)&Hout[(size_t)bi * 1024 + 512 + d] = o;
  } else {
    *(u32*)&Hout[(size_t)bi * 512 + d] = o;
  }
}

// ---------------- split-K combines (fixed ascending order -> deterministic) --
// MLP1: sum 4 partials + bias, relu, hi/lo split -> Ap2 [hi, hi, lo] (1536-wide)
__global__ __launch_bounds__(256)
void combine_mlp1(const float* __restrict__ P, const float* __restrict__ bias,
                  u16* __restrict__ Ap2) {
  const int idx = blockIdx.x * 256 + threadIdx.x;   // 262144 = 1024*512/2
  const int m = idx >> 8;
  const int n = (idx & 255) * 2;
  float s0 = 0.f, s1 = 0.f;
#pragma unroll
  for (int s = 0; s < 4; ++s) {
    const float2 v = *(const float2*)&P[(size_t)s * 524288 + m * 512 + n];
    s0 += v.x; s1 += v.y;
  }
  const float x0 = fmaxf(s0 + bias[n], 0.f);
  const float x1 = fmaxf(s1 + bias[n + 1], 0.f);
  const u16 h0 = f2bf(x0), h1 = f2bf(x1);
  const float l0 = x0 - bf2f(h0), l1 = x1 - bf2f(h1);
  const u32 hh = (u32)h0 | ((u32)h1 << 16);
  const u32 ll = (u32)f2bf(l0) | ((u32)f2bf(l1) << 16);
  const size_t base = (size_t)m * 1536 + n;
  *(u32*)&Ap2[base] = hh;
  *(u32*)&Ap2[base + 512] = hh;
  *(u32*)&Ap2[base + 1024] = ll;
}

// MLP2: sum 6 partials + bias, relu -> fp32 out
__global__ __launch_bounds__(256)
void combine_mlp2(const float* __restrict__ P, const float* __restrict__ bias,
                  float* __restrict__ out) {
  const int idx = blockIdx.x * 256 + threadIdx.x;   // 131072 = 1024*512/4
  const int m = idx >> 7;
  const int n = (idx & 127) * 4;
  float4 s = {0.f, 0.f, 0.f, 0.f};
#pragma unroll
  for (int t = 0; t < 6; ++t) {
    const float4 v = *(const float4*)&P[(size_t)t * 524288 + m * 512 + n];
    s.x += v.x; s.y += v.y; s.z += v.z; s.w += v.w;
  }
  const float4 b = *(const float4*)&bias[n];
  float4 o;
  o.x = fmaxf(s.x + b.x, 0.f);
  o.y = fmaxf(s.y + b.y, 0.f);
  o.z = fmaxf(s.z + b.z, 0.f);
  o.w = fmaxf(s.w + b.w, 0.f);
  *(float4*)&out[(size_t)m * 512 + n] = o;
}

// ---------------------------------------------------------------------------
extern "C" void kernel_launch(void* const* d_in, const int* in_sizes, int n_in,
                              void* d_out, int out_size, void* d_ws, size_t ws_size,
                              hipStream_t stream) {
  const float* gcn_inputs = (const float*)d_in[0];
  // d_in[1] = word_seq_len: unused by the reference
  const float* adj = (const float*)d_in[2];
  const int* lab = (const int*)d_in[3];
  const float* w_params = (const float*)d_in[4];
  const float* w0 = (const float*)d_in[5];
  const float* b0 = (const float*)d_in[6];
  const float* w1 = (const float*)d_in[7];
  const float* b1 = (const float*)d_in[8];
  float* out = (float*)d_out;

  // workspace layout (bytes):
  //   Wbf  [0,        25165824)  : 48*512*512 bf16
  //     P (split-K partials, <=12MB) aliases Wbf (dead after GEMM2)
  //   T    [25165824, 75497472)  : 1024 x 24576 bf16
  //     Bp1 = T+0      (512x1024 bf16)  } written AFTER last T read
  //     Bp2 = T+1MB    (512x1536 bf16)  }
  //   Ha   [75497472, +1MB) : 1024x512 bf16
  //   Hb   [76546048, +1MB) : 1024x512 bf16
  //   Ap1  [77594624, +2MB) : 1024x1024 bf16 (agg#2 DUP output)
  //   Ap2  [79691776, +3MB) : 1024x1536 bf16 (MLP1 hi/hi/lo output)
  char* ws = (char*)d_ws;
  u16* Wbf = (u16*)ws;
  float* P = (float*)ws;                      // aliases Wbf (dead by then)
  u16* T = (u16*)(ws + 25165824);
  u16* Bp1 = T;
  u16* Bp2 = (u16*)(ws + 25165824 + (1 << 20));
  u16* Ha = (u16*)(ws + 75497472);
  u16* Hb = (u16*)(ws + 76546048);
  u16* Ap1 = (u16*)(ws + 77594624);
  u16* Ap2 = (u16*)(ws + 79691776);

  cvt_f32_bf16<<<2048, 256, 0, stream>>>(w_params, Wbf, (48 * 512 * 512) / 4);
  cvt_f32_bf16<<<512, 256, 0, stream>>>(gcn_inputs, Ha, (8 * 128 * 512) / 4);

  // big einsum GEMM: M=1024, N=24576, K=512 -> 1536 blocks, XCD band map
  // GCN layer 1
  gemm_nt_bf16<0><<<1536, 256, 0, stream>>>(Ha, Wbf, T, 24576, 512, 512);
  gcn_agg<false><<<1024, 256, 0, stream>>>(T, adj, lab, Hb);
  // GCN layer 2
  gemm_nt_bf16<0><<<1536, 256, 0, stream>>>(Hb, Wbf, T, 24576, 512, 512);
  gcn_agg<true><<<1024, 256, 0, stream>>>(T, adj, lab, Ap1);   // -> A'=[H,H]

  // MLP weight hi/lo prep (T region dead now; Bp1/Bp2 alias it)
  prep_mlp_w<<<2048, 256, 0, stream>>>(w0, w1, Bp1, Bp2);

  // MLP layer 1: X1 = relu(Ha@W0^T+b0); split-K 4x256 -> 128 blocks
  dim3 g1(512 / BN, 1024 / BM, 4);
  gemm_nt_bf16<1><<<g1, 256, 0, stream>>>(Ap1, Bp1, P, 512, 1024, 256);
  combine_mlp1<<<1024, 256, 0, stream>>>(P, b0, Ap2);
  // MLP layer 2: out = relu(X1@W1^T+b1); split-K 6x256 -> 192 blocks
  dim3 g2(512 / BN, 1024 / BM, 6);
  gemm_nt_bf16<1><<<g2, 256, 0, stream>>>(Ap2, Bp2, P, 512, 1536, 256);
  combine_mlp2<<<512, 256, 0, stream>>>(P, b1, out);
}

// Round 9
// 175.331 us; speedup vs baseline: 1.0030x; 1.0030x over previous
//
#include <hip/hip_runtime.h>
#include <hip/hip_bf16.h>

// Problem constants: B=8, N=128, D=512, L=48, 2 GCN layers.
//   t = einsum('ldk,bjk->bljd', w, h)  ==  T[(b*128+j), l*512+d] = sum_k H[bj,k]*Wflat[ld,k]
//   msg[b,i,d] = sum_j adj[b,i,j] * T[b*128+j, lab[b,i,j]*512+d];  h = relu(msg/(1+deg))
//   out = relu(relu(h@w0^T+b0)@w1^T+b1)
// Big GEMM: 2-phase 128x128 MFMA + XCD L2-band map + depth-2 counted prefetch
//           + LDS bank-swizzle (16B unit ^= (row>>1)&3; inverse-swizzled global
//           source, linear gl_lds dest, swizzled ds_read -- rule 21).
// MLP: bf16 hi/lo compensation, split-K (deterministic fixed-order combine).

typedef unsigned short u16;
typedef unsigned int u32;
using bf16x8 = __bf16 __attribute__((ext_vector_type(8)));
using f32x4 = float __attribute__((ext_vector_type(4)));

__device__ __forceinline__ u16 f2bf(float f) {
  u32 u = __float_as_uint(f);
  u32 r = u + 0x7fffu + ((u >> 16) & 1u);   // round-to-nearest-even
  return (u16)(r >> 16);
}
__device__ __forceinline__ float bf2f(u16 h) {
  return __uint_as_float(((u32)h) << 16);
}

__device__ __forceinline__ void gl_lds16(const u16* g, u16* l) {
  __builtin_amdgcn_global_load_lds(
      (const __attribute__((address_space(1))) u32*)g,
      (__attribute__((address_space(3))) u32*)l, 16, 0, 0);
}

// ------ fused fp32 -> bf16 conversion: blocks <2048 do W, rest do H ---------
__global__ __launch_bounds__(256)
void cvt_all(const float* __restrict__ w_in, u16* __restrict__ w_out,
             const float* __restrict__ h_in, u16* __restrict__ h_out) {
  if (blockIdx.x < 2048) {
    const int n4 = (48 * 512 * 512) / 4;
    const int stride = 2048 * 256;
    for (int i = blockIdx.x * 256 + threadIdx.x; i < n4; i += stride) {
      float4 v = ((const float4*)w_in)[i];
      uint2 o;
      o.x = (u32)f2bf(v.x) | ((u32)f2bf(v.y) << 16);
      o.y = (u32)f2bf(v.z) | ((u32)f2bf(v.w) << 16);
      ((uint2*)w_out)[i] = o;
    }
  } else {
    const int i = (blockIdx.x - 2048) * 256 + threadIdx.x;  // 512 blocks cover exactly
    float4 v = ((const float4*)h_in)[i];
    uint2 o;
    o.x = (u32)f2bf(v.x) | ((u32)f2bf(v.y) << 16);
    o.y = (u32)f2bf(v.z) | ((u32)f2bf(v.w) << 16);
    ((uint2*)h_out)[i] = o;
  }
}

// ---------------- MLP weight prep: hi/lo split into concatenated-K layout ----
// w0 (512x512 f32) -> Bp1 (512x1024 bf16): [n,k]=hi, [n,512+k]=lo
// w1 (512x512 f32) -> Bp2 (512x1536 bf16): [n,k]=hi, [n,512+k]=lo, [n,1024+k]=hi
__global__ __launch_bounds__(256)
void prep_mlp_w(const float* __restrict__ w0, const float* __restrict__ w1,
                u16* __restrict__ Bp1, u16* __restrict__ Bp2) {
  int idx = blockIdx.x * 256 + threadIdx.x;   // grid covers 2*262144
  if (idx < 262144) {
    const int n = idx >> 9, k = idx & 511;
    const float v = w0[idx];
    const u16 hi = f2bf(v);
    const float lo = v - bf2f(hi);
    Bp1[n * 1024 + k] = hi;
    Bp1[n * 1024 + 512 + k] = f2bf(lo);
  } else {
    const int j = idx - 262144;
    const int n = j >> 9, k = j & 511;
    const float v = w1[j];
    const u16 hi = f2bf(v);
    const float lo = v - bf2f(hi);
    Bp2[n * 1536 + k] = hi;
    Bp2[n * 1536 + 512 + k] = f2bf(lo);
    Bp2[n * 1536 + 1024 + k] = hi;
  }
}

// ---------------- bf16 NT GEMM: C[m,n] = sum_k A[m,k]*B[n,k] ----------------
// 128x128 tile, BK=32, 256 threads (4 waves, 2x2), 16x16x32 MFMA, 4x4/wave.
// Depth-2 prefetch, 3 LDS buffers, counted vmcnt(4), raw s_barrier.
// Bank swizzle: physical 16B-unit p of row r holds global unit p^((r>>1)&3).
//   - stage: thread tid (row tid>>2, phys unit tid&3) loads global unit
//     (tid&3)^((tid>>3)&3); LDS dest linear (gl_lds requirement).
//   - read: logical k16=lane>>4 -> phys unit k16^((r15>>1)&3) (lane-const).
//   Spreads each 16-lane frag-read group over all 8 bank-quads (2-way = free).
// MODE 0: big einsum, 1-D grid 1536, XCD band map, bf16 C (ldc=N).
// MODE 1: split-K partial, 3-D grid, K-chunk KC, fp32 partial at C+z*1024*N.
#define BM 128
#define BN 128
#define BK 32

template <int MODE>
__global__ __launch_bounds__(256, 3)
void gemm_nt_bf16(const u16* __restrict__ A, const u16* __restrict__ B,
                  void* __restrict__ C, int N, int K, int KC) {
  __shared__ u16 sA[3][BM * BK];   // 8 KB per buffer
  __shared__ u16 sB[3][BN * BK];
  const int tid = threadIdx.x;
  const int lane = tid & 63;
  const int wid = tid >> 6;
  const int wm = wid >> 1;
  const int wn = wid & 1;

  int m0, n0, kc;
  if (MODE == 0) {
    // dispatch round-robins consecutive blockIdx across XCDs: XCD = bid % 8.
    const int bid = blockIdx.x;
    const int xcd = bid & 7;
    const int r = bid >> 3;
    m0 = (r & 7) * BM;                  // 8 m-tiles (M=1024)
    n0 = (xcd * 24 + (r >> 3)) * BN;    // 24 n-tiles per XCD band (N=24576)
    kc = 0;
  } else {
    m0 = blockIdx.y * BM;
    n0 = blockIdx.x * BN;
    kc = blockIdx.z;
  }

  const int srow = tid >> 2;
  const int scol = ((tid & 3) ^ ((tid >> 3) & 3)) * 8;   // inverse-swizzled src
  const u16* gA0 = A + (size_t)(m0 + srow) * K + kc * KC + scol;
  const u16* gA1 = A + (size_t)(m0 + 64 + srow) * K + kc * KC + scol;
  const u16* gB0 = B + (size_t)(n0 + srow) * K + kc * KC + scol;
  const u16* gB1 = B + (size_t)(n0 + 64 + srow) * K + kc * KC + scol;

  auto stage = [&](int buf, int kt) {
    const int ko = kt * BK;
    gl_lds16(gA0 + ko, &sA[buf][tid * 8]);
    gl_lds16(gA1 + ko, &sA[buf][2048 + tid * 8]);
    gl_lds16(gB0 + ko, &sB[buf][tid * 8]);
    gl_lds16(gB1 + ko, &sB[buf][2048 + tid * 8]);
  };

  f32x4 acc[4][4];
#pragma unroll
  for (int i = 0; i < 4; ++i)
#pragma unroll
    for (int j = 0; j < 4; ++j)
      acc[i][j] = (f32x4){0.f, 0.f, 0.f, 0.f};

  const int NT = KC / BK;   // 16 (MODE 0), 4 (MODE 1)

  // prologue: stage kt0, kt1; wait kt0 (kt1's 4 loads stay in flight)
  stage(0, 0);
  if (NT > 1) {
    stage(1, 1);
    asm volatile("s_waitcnt vmcnt(4)" ::: "memory");
  } else {
    asm volatile("s_waitcnt vmcnt(0)" ::: "memory");
  }
  __builtin_amdgcn_s_barrier();
  __builtin_amdgcn_sched_barrier(0);

  const int r15 = lane & 15;
  // swizzled physical column (elems): (k16 ^ ((r15>>1)&3)) * 8 -- lane-const
  const int colswz = (((lane >> 4) ^ ((r15 >> 1) & 3))) * 8;
  for (int kt = 0; kt < NT; ++kt) {
    const int buf = kt % 3;
    if (kt + 2 < NT) stage((kt + 2) % 3, kt + 2);   // depth-2 prefetch

    bf16x8 af[4], bfr[4];
#pragma unroll
    for (int mi = 0; mi < 4; ++mi)
      af[mi] = *(const bf16x8*)&sA[buf][(wm * 64 + mi * 16 + r15) * BK + colswz];
#pragma unroll
    for (int ni = 0; ni < 4; ++ni)
      bfr[ni] = *(const bf16x8*)&sB[buf][(wn * 64 + ni * 16 + r15) * BK + colswz];

#pragma unroll
    for (int mi = 0; mi < 4; ++mi)
#pragma unroll
      for (int ni = 0; ni < 4; ++ni)
        acc[mi][ni] = __builtin_amdgcn_mfma_f32_16x16x32_bf16(
            af[mi], bfr[ni], acc[mi][ni], 0, 0, 0);

    if (kt + 1 < NT) {
      // need kt+1's 4 loads done; kt+2's (if issued) may stay in flight
      if (kt + 2 < NT)
        asm volatile("s_waitcnt vmcnt(4)" ::: "memory");
      else
        asm volatile("s_waitcnt vmcnt(0)" ::: "memory");
      __builtin_amdgcn_s_barrier();
      __builtin_amdgcn_sched_barrier(0);
    }
  }

  // epilogue: C/D layout col=lane&15, row=(lane>>4)*4+reg  [m89-verified]
  const int rq = (lane >> 4) * 4;
#pragma unroll
  for (int mi = 0; mi < 4; ++mi) {
#pragma unroll
    for (int ni = 0; ni < 4; ++ni) {
      const int row = m0 + wm * 64 + mi * 16 + rq;
      const int col = n0 + wn * 64 + ni * 16 + r15;
      f32x4 v = acc[mi][ni];
      if (MODE == 0) {
        u16* Cb = (u16*)C;
        const size_t base = (size_t)row * N + col;
#pragma unroll
        for (int r = 0; r < 4; ++r)
          Cb[base + (size_t)r * N] = f2bf(v[r]);
      } else {
        float* Cf = (float*)C + (size_t)kc * 1024 * N;
#pragma unroll
        for (int r = 0; r < 4; ++r)
          Cf[(size_t)(row + r) * N + col] = v[r];
      }
    }
  }
}

// ---------------- per-row gather-reduce: msg + relu(msg/denom) -> bf16 -------
// block -> (b,i) with b = bid&7 so each XCD's L2 holds mostly one b's T slice.
// Skips adj==0 edges (bit-exact: skipped terms added exactly 0.0).
template <bool DUP>
__global__ __launch_bounds__(256)
void gcn_agg(const u16* __restrict__ T, const float* __restrict__ adj,
             const int* __restrict__ lab, u16* __restrict__ Hout) {
  const int bid = blockIdx.x;
  const int b = bid & 7;
  const int i = bid >> 3;
  const int bi = b * 128 + i;
  const int tid = threadIdx.x;
  __shared__ float s_adj[128];
  __shared__ int s_off[128];
  if (tid < 128) {
    s_adj[tid] = adj[(size_t)bi * 128 + tid];
    const int lv = lab[(size_t)bi * 128 + tid];
    s_off[tid] = ((b * 128 + tid) * 48 + lv) * 512;
  }
  __syncthreads();

  const int d = tid * 2;
  float den = 1.0f, a0 = 0.f, a1 = 0.f;
#pragma unroll 4
  for (int j = 0; j < 128; ++j) {
    const float a = s_adj[j];
    if (a != 0.0f) {              // block-uniform branch; a is exactly 1.0
      den += 1.0f;
      const u32 u = *(const u32*)&T[(size_t)s_off[j] + d];
      a0 += __uint_as_float((u & 0xffffu) << 16);
      a1 += __uint_as_float(u & 0xffff0000u);
    }
  }
  const float r = 1.0f / den;
  a0 = fmaxf(a0 * r, 0.0f);
  a1 = fmaxf(a1 * r, 0.0f);
  const u32 o = (u32)f2bf(a0) | ((u32)f2bf(a1) << 16);
  if (DUP) {
    *(u32*)&Hout[(size_t)bi * 1024 + d] = o;
    *(u32*)&Hout[(size_t)bi * 1024 + 512 + d] = o;
  } else {
    *(u32*)&Hout[(size_t)bi * 512 + d] = o;
  }
}

// ---------------- split-K combines (fixed ascending order -> deterministic) --
// MLP1: sum 8 partials + bias, relu, hi/lo split -> Ap2 [hi, hi, lo] (1536-wide)
__global__ __launch_bounds__(256)
void combine_mlp1(const float* __restrict__ P, const float* __restrict__ bias,
                  u16* __restrict__ Ap2) {
  const int idx = blockIdx.x * 256 + threadIdx.x;   // 262144 = 1024*512/2
  const int m = idx >> 8;
  const int n = (idx & 255) * 2;
  float s0 = 0.f, s1 = 0.f;
#pragma unroll
  for (int s = 0; s < 8; ++s) {
    const float2 v = *(const float2*)&P[(size_t)s * 524288 + m * 512 + n];
    s0 += v.x; s1 += v.y;
  }
  const float x0 = fmaxf(s0 + bias[n], 0.f);
  const float x1 = fmaxf(s1 + bias[n + 1], 0.f);
  const u16 h0 = f2bf(x0), h1 = f2bf(x1);
  const float l0 = x0 - bf2f(h0), l1 = x1 - bf2f(h1);
  const u32 hh = (u32)h0 | ((u32)h1 << 16);
  const u32 ll = (u32)f2bf(l0) | ((u32)f2bf(l1) << 16);
  const size_t base = (size_t)m * 1536 + n;
  *(u32*)&Ap2[base] = hh;
  *(u32*)&Ap2[base + 512] = hh;
  *(u32*)&Ap2[base + 1024] = ll;
}

// MLP2: sum 12 partials + bias, relu -> fp32 out
__global__ __launch_bounds__(256)
void combine_mlp2(const float* __restrict__ P, const float* __restrict__ bias,
                  float* __restrict__ out) {
  const int idx = blockIdx.x * 256 + threadIdx.x;   // 131072 = 1024*512/4
  const int m = idx >> 7;
  const int n = (idx & 127) * 4;
  float4 s = {0.f, 0.f, 0.f, 0.f};
#pragma unroll
  for (int t = 0; t < 12; ++t) {
    const float4 v = *(const float4*)&P[(size_t)t * 524288 + m * 512 + n];
    s.x += v.x; s.y += v.y; s.z += v.z; s.w += v.w;
  }
  const float4 b = *(const float4*)&bias[n];
  float4 o;
  o.x = fmaxf(s.x + b.x, 0.f);
  o.y = fmaxf(s.y + b.y, 0.f);
  o.z = fmaxf(s.z + b.z, 0.f);
  o.w = fmaxf(s.w + b.w, 0.f);
  *(float4*)&out[(size_t)m * 512 + n] = o;
}

// ---------------------------------------------------------------------------
extern "C" void kernel_launch(void* const* d_in, const int* in_sizes, int n_in,
                              void* d_out, int out_size, void* d_ws, size_t ws_size,
                              hipStream_t stream) {
  const float* gcn_inputs = (const float*)d_in[0];
  // d_in[1] = word_seq_len: unused by the reference
  const float* adj = (const float*)d_in[2];
  const int* lab = (const int*)d_in[3];
  const float* w_params = (const float*)d_in[4];
  const float* w0 = (const float*)d_in[5];
  const float* b0 = (const float*)d_in[6];
  const float* w1 = (const float*)d_in[7];
  const float* b1 = (const float*)d_in[8];
  float* out = (float*)d_out;

  // workspace layout (bytes):
  //   Wbf  [0,        25165824)  : 48*512*512 bf16
  //     P (split-K partials, <=24MB) aliases Wbf (dead after GEMM2)
  //   T    [25165824, 75497472)  : 1024 x 24576 bf16
  //     Bp1 = T+0      (512x1024 bf16)  } written AFTER last T read
  //     Bp2 = T+1MB    (512x1536 bf16)  }
  //   Ha   [75497472, +1MB) : 1024x512 bf16
  //   Hb   [76546048, +1MB) : 1024x512 bf16
  //   Ap1  [77594624, +2MB) : 1024x1024 bf16 (agg#2 DUP output)
  //   Ap2  [79691776, +3MB) : 1024x1536 bf16 (MLP1 hi/hi/lo output)
  char* ws = (char*)d_ws;
  u16* Wbf = (u16*)ws;
  float* P = (float*)ws;                      // aliases Wbf (dead by then)
  u16* T = (u16*)(ws + 25165824);
  u16* Bp1 = T;
  u16* Bp2 = (u16*)(ws + 25165824 + (1 << 20));
  u16* Ha = (u16*)(ws + 75497472);
  u16* Hb = (u16*)(ws + 76546048);
  u16* Ap1 = (u16*)(ws + 77594624);
  u16* Ap2 = (u16*)(ws + 79691776);

  cvt_all<<<2560, 256, 0, stream>>>(w_params, Wbf, gcn_inputs, Ha);

  // big einsum GEMM: M=1024, N=24576, K=512 -> 1536 blocks, XCD band map
  // GCN layer 1
  gemm_nt_bf16<0><<<1536, 256, 0, stream>>>(Ha, Wbf, T, 24576, 512, 512);
  gcn_agg<false><<<1024, 256, 0, stream>>>(T, adj, lab, Hb);
  // GCN layer 2
  gemm_nt_bf16<0><<<1536, 256, 0, stream>>>(Hb, Wbf, T, 24576, 512, 512);
  gcn_agg<true><<<1024, 256, 0, stream>>>(T, adj, lab, Ap1);   // -> A'=[H,H]

  // MLP weight hi/lo prep (T region dead now; Bp1/Bp2 alias it)
  prep_mlp_w<<<2048, 256, 0, stream>>>(w0, w1, Bp1, Bp2);

  // MLP layer 1: X1 = relu(Ha@W0^T+b0); split-K 8x128 -> 256 blocks
  dim3 g1(512 / BN, 1024 / BM, 8);
  gemm_nt_bf16<1><<<g1, 256, 0, stream>>>(Ap1, Bp1, P, 512, 1024, 128);
  combine_mlp1<<<1024, 256, 0, stream>>>(P, b0, Ap2);
  // MLP layer 2: out = relu(X1@W1^T+b1); split-K 12x128 -> 384 blocks
  dim3 g2(512 / BN, 1024 / BM, 12);
  gemm_nt_bf16<1><<<g2, 256, 0, stream>>>(Ap2, Bp2, P, 512, 1536, 128);
  combine_mlp2<<<512, 256, 0, stream>>>(P, b1, out);
}

// Round 10
// 170.479 us; speedup vs baseline: 1.0315x; 1.0285x over previous
//
#include <hip/hip_runtime.h>
#include <hip/hip_bf16.h>

// Problem constants: B=8, N=128, D=512, L=48, 2 GCN layers.
//   t = einsum('ldk,bjk->bljd', w, h)  ==  T[(b*128+j), l*512+d] = sum_k H[bj,k]*Wflat[ld,k]
//   msg[b,i,d] = sum_j adj[b,i,j] * T[b*128+j, lab[b,i,j]*512+d];  h = relu(msg/(1+deg))
//   out = relu(relu(h@w0^T+b0)@w1^T+b1)
// Big GEMM: 2-phase 128x128 MFMA + XCD L2-band map + depth-2 counted prefetch
//           + LDS bank-swizzle (conflicts measured 0). 43.3us/dispatch, 596 TF.
// MLP: bf16 hi/lo compensation, split-K S=4/6 KC=256 (round-7 measured optimum).
// cvt_all fuses: W f32->bf16, H f32->bf16, MLP weight hi/lo prep (one dispatch).

typedef unsigned short u16;
typedef unsigned int u32;
using bf16x8 = __bf16 __attribute__((ext_vector_type(8)));
using f32x4 = float __attribute__((ext_vector_type(4)));

__device__ __forceinline__ u16 f2bf(float f) {
  u32 u = __float_as_uint(f);
  u32 r = u + 0x7fffu + ((u >> 16) & 1u);   // round-to-nearest-even
  return (u16)(r >> 16);
}
__device__ __forceinline__ float bf2f(u16 h) {
  return __uint_as_float(((u32)h) << 16);
}

__device__ __forceinline__ void gl_lds16(const u16* g, u16* l) {
  __builtin_amdgcn_global_load_lds(
      (const __attribute__((address_space(1))) u32*)g,
      (__attribute__((address_space(3))) u32*)l, 16, 0, 0);
}

// ------ fused prep: W cvt | H cvt | MLP weight hi/lo split -------------------
// blocks [0,2048): w_params f32->bf16 (grid-stride)
// blocks [2048,2560): gcn_inputs f32->bf16 (exact cover)
// blocks [2560,4608): w0/w1 hi/lo split into Bp1/Bp2 (exact cover)
__global__ __launch_bounds__(256)
void cvt_all(const float* __restrict__ w_in, u16* __restrict__ w_out,
             const float* __restrict__ h_in, u16* __restrict__ h_out,
             const float* __restrict__ w0, const float* __restrict__ w1,
             u16* __restrict__ Bp1, u16* __restrict__ Bp2) {
  const int bx = blockIdx.x;
  if (bx < 2048) {
    const int n4 = (48 * 512 * 512) / 4;
    const int stride = 2048 * 256;
    for (int i = bx * 256 + threadIdx.x; i < n4; i += stride) {
      float4 v = ((const float4*)w_in)[i];
      uint2 o;
      o.x = (u32)f2bf(v.x) | ((u32)f2bf(v.y) << 16);
      o.y = (u32)f2bf(v.z) | ((u32)f2bf(v.w) << 16);
      ((uint2*)w_out)[i] = o;
    }
  } else if (bx < 2560) {
    const int i = (bx - 2048) * 256 + threadIdx.x;  // 512 blocks cover exactly
    float4 v = ((const float4*)h_in)[i];
    uint2 o;
    o.x = (u32)f2bf(v.x) | ((u32)f2bf(v.y) << 16);
    o.y = (u32)f2bf(v.z) | ((u32)f2bf(v.w) << 16);
    ((uint2*)h_out)[i] = o;
  } else {
    const int idx = (bx - 2560) * 256 + threadIdx.x;  // covers 2*262144
    if (idx < 262144) {
      const int n = idx >> 9, k = idx & 511;
      const float v = w0[idx];
      const u16 hi = f2bf(v);
      const float lo = v - bf2f(hi);
      Bp1[n * 1024 + k] = hi;
      Bp1[n * 1024 + 512 + k] = f2bf(lo);
    } else {
      const int j = idx - 262144;
      const int n = j >> 9, k = j & 511;
      const float v = w1[j];
      const u16 hi = f2bf(v);
      const float lo = v - bf2f(hi);
      Bp2[n * 1536 + k] = hi;
      Bp2[n * 1536 + 512 + k] = f2bf(lo);
      Bp2[n * 1536 + 1024 + k] = hi;
    }
  }
}

// ---------------- bf16 NT GEMM: C[m,n] = sum_k A[m,k]*B[n,k] ----------------
// 128x128 tile, BK=32, 256 threads (4 waves, 2x2), 16x16x32 MFMA, 4x4/wave.
// Depth-2 prefetch, 3 LDS buffers, counted vmcnt(4), raw s_barrier.
// Bank swizzle: physical 16B-unit p of row r holds global unit p^((r>>1)&3)
// (inverse-swizzled global src, linear gl_lds dest, swizzled ds_read; rule 21).
// MODE 0: big einsum, 1-D grid 1536, XCD band map, bf16 C (ldc=N).
// MODE 1: split-K partial, 3-D grid, K-chunk KC, fp32 partial at C+z*1024*N.
#define BM 128
#define BN 128
#define BK 32

template <int MODE>
__global__ __launch_bounds__(256, 3)
void gemm_nt_bf16(const u16* __restrict__ A, const u16* __restrict__ B,
                  void* __restrict__ C, int N, int K, int KC) {
  __shared__ u16 sA[3][BM * BK];   // 8 KB per buffer
  __shared__ u16 sB[3][BN * BK];
  const int tid = threadIdx.x;
  const int lane = tid & 63;
  const int wid = tid >> 6;
  const int wm = wid >> 1;
  const int wn = wid & 1;

  int m0, n0, kc;
  if (MODE == 0) {
    // dispatch round-robins consecutive blockIdx across XCDs: XCD = bid % 8.
    const int bid = blockIdx.x;
    const int xcd = bid & 7;
    const int r = bid >> 3;
    m0 = (r & 7) * BM;                  // 8 m-tiles (M=1024)
    n0 = (xcd * 24 + (r >> 3)) * BN;    // 24 n-tiles per XCD band (N=24576)
    kc = 0;
  } else {
    m0 = blockIdx.y * BM;
    n0 = blockIdx.x * BN;
    kc = blockIdx.z;
  }

  const int srow = tid >> 2;
  const int scol = ((tid & 3) ^ ((tid >> 3) & 3)) * 8;   // inverse-swizzled src
  const u16* gA0 = A + (size_t)(m0 + srow) * K + kc * KC + scol;
  const u16* gA1 = A + (size_t)(m0 + 64 + srow) * K + kc * KC + scol;
  const u16* gB0 = B + (size_t)(n0 + srow) * K + kc * KC + scol;
  const u16* gB1 = B + (size_t)(n0 + 64 + srow) * K + kc * KC + scol;

  auto stage = [&](int buf, int kt) {
    const int ko = kt * BK;
    gl_lds16(gA0 + ko, &sA[buf][tid * 8]);
    gl_lds16(gA1 + ko, &sA[buf][2048 + tid * 8]);
    gl_lds16(gB0 + ko, &sB[buf][tid * 8]);
    gl_lds16(gB1 + ko, &sB[buf][2048 + tid * 8]);
  };

  f32x4 acc[4][4];
#pragma unroll
  for (int i = 0; i < 4; ++i)
#pragma unroll
    for (int j = 0; j < 4; ++j)
      acc[i][j] = (f32x4){0.f, 0.f, 0.f, 0.f};

  const int NT = KC / BK;   // 16 (MODE 0), 8 (MODE 1)

  // prologue: stage kt0, kt1; wait kt0 (kt1's 4 loads stay in flight)
  stage(0, 0);
  if (NT > 1) {
    stage(1, 1);
    asm volatile("s_waitcnt vmcnt(4)" ::: "memory");
  } else {
    asm volatile("s_waitcnt vmcnt(0)" ::: "memory");
  }
  __builtin_amdgcn_s_barrier();
  __builtin_amdgcn_sched_barrier(0);

  const int r15 = lane & 15;
  // swizzled physical column (elems): (k16 ^ ((r15>>1)&3)) * 8 -- lane-const
  const int colswz = (((lane >> 4) ^ ((r15 >> 1) & 3))) * 8;
  for (int kt = 0; kt < NT; ++kt) {
    const int buf = kt % 3;
    if (kt + 2 < NT) stage((kt + 2) % 3, kt + 2);   // depth-2 prefetch

    bf16x8 af[4], bfr[4];
#pragma unroll
    for (int mi = 0; mi < 4; ++mi)
      af[mi] = *(const bf16x8*)&sA[buf][(wm * 64 + mi * 16 + r15) * BK + colswz];
#pragma unroll
    for (int ni = 0; ni < 4; ++ni)
      bfr[ni] = *(const bf16x8*)&sB[buf][(wn * 64 + ni * 16 + r15) * BK + colswz];

#pragma unroll
    for (int mi = 0; mi < 4; ++mi)
#pragma unroll
      for (int ni = 0; ni < 4; ++ni)
        acc[mi][ni] = __builtin_amdgcn_mfma_f32_16x16x32_bf16(
            af[mi], bfr[ni], acc[mi][ni], 0, 0, 0);

    if (kt + 1 < NT) {
      // need kt+1's 4 loads done; kt+2's (if issued) may stay in flight
      if (kt + 2 < NT)
        asm volatile("s_waitcnt vmcnt(4)" ::: "memory");
      else
        asm volatile("s_waitcnt vmcnt(0)" ::: "memory");
      __builtin_amdgcn_s_barrier();
      __builtin_amdgcn_sched_barrier(0);
    }
  }

  // epilogue: C/D layout col=lane&15, row=(lane>>4)*4+reg  [m89-verified]
  const int rq = (lane >> 4) * 4;
#pragma unroll
  for (int mi = 0; mi < 4; ++mi) {
#pragma unroll
    for (int ni = 0; ni < 4; ++ni) {
      const int row = m0 + wm * 64 + mi * 16 + rq;
      const int col = n0 + wn * 64 + ni * 16 + r15;
      f32x4 v = acc[mi][ni];
      if (MODE == 0) {
        u16* Cb = (u16*)C;
        const size_t base = (size_t)row * N + col;
#pragma unroll
        for (int r = 0; r < 4; ++r)
          Cb[base + (size_t)r * N] = f2bf(v[r]);
      } else {
        float* Cf = (float*)C + (size_t)kc * 1024 * N;
#pragma unroll
        for (int r = 0; r < 4; ++r)
          Cf[(size_t)(row + r) * N + col] = v[r];
      }
    }
  }
}

// ---------------- per-row gather-reduce: msg + relu(msg/denom) -> bf16 -------
// block -> (b,i) with b = bid&7 so each XCD's L2 holds mostly one b's T slice.
// Skips adj==0 edges (bit-exact: skipped terms added exactly 0.0).
template <bool DUP>
__global__ __launch_bounds__(256)
void gcn_agg(const u16* __restrict__ T, const float* __restrict__ adj,
             const int* __restrict__ lab, u16* __restrict__ Hout) {
  const int bid = blockIdx.x;
  const int b = bid & 7;
  const int i = bid >> 3;
  const int bi = b * 128 + i;
  const int tid = threadIdx.x;
  __shared__ float s_adj[128];
  __shared__ int s_off[128];
  if (tid < 128) {
    s_adj[tid] = adj[(size_t)bi * 128 + tid];
    const int lv = lab[(size_t)bi * 128 + tid];
    s_off[tid] = ((b * 128 + tid) * 48 + lv) * 512;
  }
  __syncthreads();

  const int d = tid * 2;
  float den = 1.0f, a0 = 0.f, a1 = 0.f;
#pragma unroll 4
  for (int j = 0; j < 128; ++j) {
    const float a = s_adj[j];
    if (a != 0.0f) {              // block-uniform branch; a is exactly 1.0
      den += 1.0f;
      const u32 u = *(const u32*)&T[(size_t)s_off[j] + d];
      a0 += __uint_as_float((u & 0xffffu) << 16);
      a1 += __uint_as_float(u & 0xffff0000u);
    }
  }
  const float r = 1.0f / den;
  a0 = fmaxf(a0 * r, 0.0f);
  a1 = fmaxf(a1 * r, 0.0f);
  const u32 o = (u32)f2bf(a0) | ((u32)f2bf(a1) << 16);
  if (DUP) {
    *(u32*)&Hout[(size_t)bi * 1024 + d] = o;
    *(u32*)&Hout[(size_t)bi * 1024 + 512 + d] = o;
  } else {
    *(u32*)&Hout[(size_t)bi * 512 + d] = o;
  }
}

// ---------------- split-K combines (fixed ascending order -> deterministic) --
// MLP1: sum 4 partials + bias, relu, hi/lo split -> Ap2 [hi, hi, lo] (1536-wide)
__global__ __launch_bounds__(256)
void combine_mlp1(const float* __restrict__ P, const float* __restrict__ bias,
                  u16* __restrict__ Ap2) {
  const int idx = blockIdx.x * 256 + threadIdx.x;   // 262144 = 1024*512/2
  const int m = idx >> 8;
  const int n = (idx & 255) * 2;
  float s0 = 0.f, s1 = 0.f;
#pragma unroll
  for (int s = 0; s < 4; ++s) {
    const float2 v = *(const float2*)&P[(size_t)s * 524288 + m * 512 + n];
    s0 += v.x; s1 += v.y;
  }
  const float x0 = fmaxf(s0 + bias[n], 0.f);
  const float x1 = fmaxf(s1 + bias[n + 1], 0.f);
  const u16 h0 = f2bf(x0), h1 = f2bf(x1);
  const float l0 = x0 - bf2f(h0), l1 = x1 - bf2f(h1);
  const u32 hh = (u32)h0 | ((u32)h1 << 16);
  const u32 ll = (u32)f2bf(l0) | ((u32)f2bf(l1) << 16);
  const size_t base = (size_t)m * 1536 + n;
  *(u32*)&Ap2[base] = hh;
  *(u32*)&Ap2[base + 512] = hh;
  *(u32*)&Ap2[base + 1024] = ll;
}

// MLP2: sum 6 partials + bias, relu -> fp32 out
__global__ __launch_bounds__(256)
void combine_mlp2(const float* __restrict__ P, const float* __restrict__ bias,
                  float* __restrict__ out) {
  const int idx = blockIdx.x * 256 + threadIdx.x;   // 131072 = 1024*512/4
  const int m = idx >> 7;
  const int n = (idx & 127) * 4;
  float4 s = {0.f, 0.f, 0.f, 0.f};
#pragma unroll
  for (int t = 0; t < 6; ++t) {
    const float4 v = *(const float4*)&P[(size_t)t * 524288 + m * 512 + n];
    s.x += v.x; s.y += v.y; s.z += v.z; s.w += v.w;
  }
  const float4 b = *(const float4*)&bias[n];
  float4 o;
  o.x = fmaxf(s.x + b.x, 0.f);
  o.y = fmaxf(s.y + b.y, 0.f);
  o.z = fmaxf(s.z + b.z, 0.f);
  o.w = fmaxf(s.w + b.w, 0.f);
  *(float4*)&out[(size_t)m * 512 + n] = o;
}

// ---------------------------------------------------------------------------
extern "C" void kernel_launch(void* const* d_in, const int* in_sizes, int n_in,
                              void* d_out, int out_size, void* d_ws, size_t ws_size,
                              hipStream_t stream) {
  const float* gcn_inputs = (const float*)d_in[0];
  // d_in[1] = word_seq_len: unused by the reference
  const float* adj = (const float*)d_in[2];
  const int* lab = (const int*)d_in[3];
  const float* w_params = (const float*)d_in[4];
  const float* w0 = (const float*)d_in[5];
  const float* b0 = (const float*)d_in[6];
  const float* w1 = (const float*)d_in[7];
  const float* b1 = (const float*)d_in[8];
  float* out = (float*)d_out;

  // workspace layout (bytes):
  //   Wbf  [0,        25165824)  : 48*512*512 bf16
  //     P (split-K partials, <=12MB) aliases Wbf (dead after GEMM2)
  //   T    [25165824, 75497472)  : 1024 x 24576 bf16
  //   Ha   [75497472, +1MB) : 1024x512 bf16
  //   Hb   [76546048, +1MB) : 1024x512 bf16
  //   Ap1  [77594624, +2MB) : 1024x1024 bf16 (agg#2 DUP output)
  //   Ap2  [79691776, +3MB) : 1024x1536 bf16 (MLP1 hi/hi/lo output)
  //   Bp1  [82837504, +1MB) : 512x1024 bf16 (w0 hi/lo)
  //   Bp2  [83886080, +1.5MB): 512x1536 bf16 (w1 hi/lo/hi)
  char* ws = (char*)d_ws;
  u16* Wbf = (u16*)ws;
  float* P = (float*)ws;                      // aliases Wbf (dead by then)
  u16* T = (u16*)(ws + 25165824);
  u16* Ha = (u16*)(ws + 75497472);
  u16* Hb = (u16*)(ws + 76546048);
  u16* Ap1 = (u16*)(ws + 77594624);
  u16* Ap2 = (u16*)(ws + 79691776);
  u16* Bp1 = (u16*)(ws + 82837504);
  u16* Bp2 = (u16*)(ws + 83886080);

  // one fused conversion dispatch: W cvt + H cvt + MLP weight prep
  cvt_all<<<4608, 256, 0, stream>>>(w_params, Wbf, gcn_inputs, Ha,
                                    w0, w1, Bp1, Bp2);

  // big einsum GEMM: M=1024, N=24576, K=512 -> 1536 blocks, XCD band map
  // GCN layer 1
  gemm_nt_bf16<0><<<1536, 256, 0, stream>>>(Ha, Wbf, T, 24576, 512, 512);
  gcn_agg<false><<<1024, 256, 0, stream>>>(T, adj, lab, Hb);
  // GCN layer 2
  gemm_nt_bf16<0><<<1536, 256, 0, stream>>>(Hb, Wbf, T, 24576, 512, 512);
  gcn_agg<true><<<1024, 256, 0, stream>>>(T, adj, lab, Ap1);   // -> A'=[H,H]

  // MLP layer 1: X1 = relu(Ha@W0^T+b0); split-K 4x256 -> 128 blocks
  dim3 g1(512 / BN, 1024 / BM, 4);
  gemm_nt_bf16<1><<<g1, 256, 0, stream>>>(Ap1, Bp1, P, 512, 1024, 256);
  combine_mlp1<<<1024, 256, 0, stream>>>(P, b0, Ap2);
  // MLP layer 2: out = relu(X1@W1^T+b1); split-K 6x256 -> 192 blocks
  dim3 g2(512 / BN, 1024 / BM, 6);
  gemm_nt_bf16<1><<<g2, 256, 0, stream>>>(Ap2, Bp2, P, 512, 1536, 256);
  combine_mlp2<<<512, 256, 0, stream>>>(P, b1, out);
}